// Round 8
// baseline (2114.178 us; speedup 1.0000x reference)
//
#include <hip/hip_runtime.h>
#include <hip/hip_bf16.h>
#include <hip/hip_fp16.h>
#include <math.h>

#define BB 128
#define TT 1024
#define DIN 64
#define HH 256
#define EE 32
#define BT (BB * TT)

typedef unsigned int uint;
typedef unsigned char uchar;
typedef _Float16 half2v __attribute__((ext_vector_type(2)));

__device__ __forceinline__ int dot4(uint a, uint b, int c) {
  return __builtin_amdgcn_sdot4((int)a, (int)b, c, false);
}
__device__ __forceinline__ uint pkh(float a, float b) {
  return __builtin_bit_cast(uint, __builtin_amdgcn_cvt_pkrtz(a, b));
}
__device__ __forceinline__ half2v uph(uint u) { return __builtin_bit_cast(half2v, u); }
__device__ __forceinline__ float fdot2u(uint a, uint b, float c) {
  return __builtin_amdgcn_fdot2(uph(a), uph(b), c, false);
}
#define IDPP(v, c) __builtin_amdgcn_mov_dpp((v), (c), 0xF, 0xF, true)
__device__ __forceinline__ int qsum(int v) {  // quad butterfly sum (VALU only)
  v += IDPP(v, 0xB1);  // xor 1
  v += IDPP(v, 0x4E);  // xor 2
  return v;
}
__device__ __forceinline__ float rcp_f(float x) { return __builtin_amdgcn_rcpf(x); }
__device__ __forceinline__ float sigm(float x) { return rcp_f(1.0f + __expf(-x)); }
__device__ __forceinline__ float tanh_f(float x) {
  return 1.0f - 2.0f * rcp_f(__expf(2.0f * x) + 1.0f);
}

// ---------- Wfold = W_proj @ W_ih (fp32) ----------
__global__ void fold_f32(const float* __restrict__ Wproj, const float* __restrict__ Wih,
                         float* __restrict__ Wfold) {
  int idx = blockIdx.x * blockDim.x + threadIdx.x;
  if (idx >= 64 * 1024) return;
  int d = idx >> 10, n = idx & 1023;
  float a = 0.f;
  for (int k = 0; k < 256; ++k) a += Wproj[d * 256 + k] * Wih[k * 1024 + n];
  Wfold[d * 1024 + n] = a;
}

// bfold[n] = b_proj @ W_ih + b_lstm
__global__ void bfold_kernel(const float* __restrict__ bproj, const float* __restrict__ Wih,
                             const float* __restrict__ blstm, float* __restrict__ bfold) {
  int n = blockIdx.x * blockDim.x + threadIdx.x;
  if (n >= 1024) return;
  float a = blstm[n];
  for (int k = 0; k < 256; ++k) a += bproj[k] * Wih[k * 1024 + n];
  bfold[n] = a;
}

// ---------- quantize weights, per-matrix scales ----------
// WhQ (scan, reg-resident): uint idx ((c*4)+q)*16 + m*4 + mm; c<1024 = Whh col (ifgo),
//   c in [1024,1280) = Whg col. rows k = q*64 + m*16 + mm*4 + {0..3}.
// XQ (pre): uint idx c*16 + k4 identity; c<1024 Wfold col, else Wmk col (K=64).
// EQ (pre): uint idx c*8 + k4 identity (K=32).
__global__ __launch_bounds__(1024) void quant_all(
    const float* __restrict__ Whh, const float* __restrict__ Whg,
    const float* __restrict__ Wfold, const float* __restrict__ Wmk,
    const float* __restrict__ We,
    uint* __restrict__ WhQ, uint* __restrict__ XQ, uint* __restrict__ EQ,
    float* __restrict__ scales) {
  const int bid = blockIdx.x, tid = threadIdx.x;
  const float* src;
  int nelem;
  switch (bid) {
    case 0: src = Whh;   nelem = 262144; break;
    case 1: src = Whg;   nelem = 65536;  break;
    case 2: src = Wfold; nelem = 65536;  break;
    case 3: src = Wmk;   nelem = 16384;  break;
    default: src = We;   nelem = 8192;   break;
  }
  float m = 0.f;
  for (int i = tid; i < nelem; i += 1024) m = fmaxf(m, fabsf(src[i]));
#pragma unroll
  for (int d = 1; d < 64; d <<= 1) m = fmaxf(m, __shfl_xor(m, d));
  __shared__ float wm[16];
  if ((tid & 63) == 0) wm[tid >> 6] = m;
  __syncthreads();
  float mg = wm[0];
#pragma unroll
  for (int i = 1; i < 16; ++i) mg = fmaxf(mg, wm[i]);
  mg = fmaxf(mg, 1e-8f);
  if (tid == 0) scales[bid] = mg * (1.0f / 127.0f);
  const float inv = 127.0f / mg;

  if (bid == 0) {  // Whh -> WhQ[0..65536) frag layout
    for (int i = tid; i < 65536; i += 1024) {
      int C = i >> 4, r = i & 15;
      int c = C >> 2, q = C & 3, mI = r >> 2, mm = r & 3;
      int k4 = q * 16 + mI * 4 + mm;
      uint d = 0;
#pragma unroll
      for (int bb = 0; bb < 4; ++bb) {
        int qv = __float2int_rn(Whh[(4 * k4 + bb) * 1024 + c] * inv);
        qv = max(-127, min(127, qv));
        d |= ((uint)(qv & 0xff)) << (8 * bb);
      }
      WhQ[i] = d;
    }
  } else if (bid == 1) {  // Whg -> WhQ[65536..81920) frag layout
    for (int i = tid; i < 16384; i += 1024) {
      int j = i >> 6, rr = i & 63;
      int q = rr >> 4, mI = (rr >> 2) & 3, mm = rr & 3;
      int k4 = q * 16 + mI * 4 + mm;
      uint d = 0;
#pragma unroll
      for (int bb = 0; bb < 4; ++bb) {
        int qv = __float2int_rn(Whg[(4 * k4 + bb) * 256 + j] * inv);
        qv = max(-127, min(127, qv));
        d |= ((uint)(qv & 0xff)) << (8 * bb);
      }
      WhQ[65536 + i] = d;
    }
  } else if (bid == 2) {  // Wfold -> XQ[0..16384) identity k4
    for (int i = tid; i < 16384; i += 1024) {
      int c = i >> 4, k4 = i & 15;
      uint d = 0;
#pragma unroll
      for (int bb = 0; bb < 4; ++bb) {
        int qv = __float2int_rn(Wfold[(4 * k4 + bb) * 1024 + c] * inv);
        qv = max(-127, min(127, qv));
        d |= ((uint)(qv & 0xff)) << (8 * bb);
      }
      XQ[i] = d;
    }
  } else if (bid == 3) {  // Wmk -> XQ[16384..20480)
    for (int i = tid; i < 4096; i += 1024) {
      int j = i >> 4, k4 = i & 15;
      uint d = 0;
#pragma unroll
      for (int bb = 0; bb < 4; ++bb) {
        int qv = __float2int_rn(Wmk[(4 * k4 + bb) * 256 + j] * inv);
        qv = max(-127, min(127, qv));
        d |= ((uint)(qv & 0xff)) << (8 * bb);
      }
      XQ[16384 + i] = d;
    }
  } else {  // We -> EQ[0..2048)
    for (int i = tid; i < 2048; i += 1024) {
      int c = i >> 3, k4 = i & 7;
      uint d = 0;
#pragma unroll
      for (int bb = 0; bb < 4; ++bb) {
        int qv = __float2int_rn(We[(4 * k4 + bb) * 256 + c] * inv);
        qv = max(-127, min(127, qv));
        d |= ((uint)(qv & 0xff)) << (8 * bb);
      }
      EQ[i] = d;
    }
  }
}

// ---------- pack Wp1 [256][128] -> f16 k-pairs: WQ[j*128 + kp] ----------
__global__ void pack_wp1h(const float* __restrict__ Wp1, uint* __restrict__ WQ) {
  int idx = blockIdx.x * blockDim.x + threadIdx.x;
  if (idx >= 16384) return;
  int j = idx >> 7, kp = idx & 127;
  WQ[idx] = pkh(Wp1[(2 * kp) * 128 + j], Wp1[(2 * kp + 1) * 128 + j]);
}

// ---------- per-(b,t) input quantization + scl={xsc,esc,fac,0} ----------
__global__ __launch_bounds__(256) void prep_inputs(
    const float* __restrict__ x, const float* __restrict__ ev, const float* __restrict__ td,
    const float* __restrict__ decay, uint* __restrict__ xq, uint* __restrict__ eq,
    float4* __restrict__ scl) {
  int wid = threadIdx.x >> 6, lane = threadIdx.x & 63;
  int bt = blockIdx.x * 4 + wid;
  if (bt >= BT) return;
  float xv = x[(size_t)bt * DIN + lane];
  float evv = (lane < EE) ? ev[(size_t)bt * EE + lane] : 0.0f;
  float ax = fabsf(xv), ae = fabsf(evv);
#pragma unroll
  for (int m = 1; m < 64; m <<= 1) {
    ax = fmaxf(ax, __shfl_xor(ax, m));
    ae = fmaxf(ae, __shfl_xor(ae, m));
  }
  float mgx = fmaxf(ax, 1e-8f), mge = fmaxf(ae, 1e-8f);
  int qx = __float2int_rn(xv * (127.0f / mgx));
  qx = max(-127, min(127, qx));
  int qe = __float2int_rn(evv * (127.0f / mge));
  qe = max(-127, min(127, qe));
  uint dx = 0, de = 0;
#pragma unroll
  for (int b = 0; b < 4; ++b) dx |= ((uint)(__shfl(qx, lane * 4 + b) & 0xff)) << (8 * b);
#pragma unroll
  for (int b = 0; b < 4; ++b) de |= ((uint)(__shfl(qe, lane * 4 + b) & 0xff)) << (8 * b);
  if (lane < 16) xq[(size_t)bt * 16 + lane] = dx;
  if (lane < 8) eq[(size_t)bt * 8 + lane] = de;
  if (lane == 0) {
    float sp = log1pf(__expf(decay[0]));
    scl[bt] = make_float4(mgx * (1.0f / 127.0f), mge * (1.0f / 127.0f),
                          __expf(-sp * td[bt]), 0.0f);
  }
}

// ---------- output 2: first temporal difference ----------
__global__ void d1_kernel(const float* __restrict__ x, float* __restrict__ out2) {
  int idx = blockIdx.x * blockDim.x + threadIdx.x;
  const int per_t = DIN / 4;
  if (idx >= BB * TT * per_t) return;
  int t = (idx / per_t) % TT;
  float4 cur = reinterpret_cast<const float4*>(x)[idx];
  float4 res;
  if (t == 0) {
    res = make_float4(0.f, 0.f, 0.f, 0.f);
  } else {
    float4 prv = reinterpret_cast<const float4*>(x)[idx - per_t];
    res = make_float4(cur.x - prv.x, cur.y - prv.y, cur.z - prv.z, cur.w - prv.w);
  }
  reinterpret_cast<float4*>(out2)[idx] = res;
}

// ---------- precompute x/e-side per (bt, j): {f16 ifgo preacts+bias, mkS, EF} ----------
// 1024 thr = 256 j x 4 K-quarters q; DPP quad-reduce; lane q=0 stores the record.
__global__ __launch_bounds__(1024) void pre2(
    int t0, int lsteps,
    const uint* __restrict__ XQ, const uint* __restrict__ EQ,
    const float* __restrict__ scales, const float* __restrict__ bfold,
    const float* __restrict__ bmk, const float* __restrict__ be,
    const uint* __restrict__ xq, const uint* __restrict__ eqp,
    const float4* __restrict__ scl, uint4* __restrict__ pre) {
  const int tid = threadIdx.x;
  const int j = tid >> 2, q = tid & 3;

  uint4 wx[4];  // ifgo gate g, this K-quarter (rows q*16..q*16+15)
#pragma unroll
  for (int g = 0; g < 4; ++g)
    wx[g] = *(const uint4*)(XQ + (g * 256 + j) * 16 + q * 4);
  const uint4 wmv = *(const uint4*)(XQ + 16384 + j * 16 + q * 4);
  const uint2 wev = *(const uint2*)(EQ + j * 8 + q * 2);
  float bf[4];
#pragma unroll
  for (int g = 0; g < 4; ++g) bf[g] = bfold[g * 256 + j];
  const float bmkv = bmk[j], bev = be[j];
  const float sXF = scales[2], sMK = scales[3], sE = scales[4];
  const int steps = 1 << lsteps;

  for (int it = 0; it < 64; ++it) {
    const int idx = blockIdx.x * 64 + it;
    const int b = idx >> lsteps, tl = idx & (steps - 1);
    const int bt = b * TT + t0 + tl;
    const uint4 X = *(const uint4*)(xq + (size_t)bt * 16 + q * 4);
    const uint2 E = *(const uint2*)(eqp + (size_t)bt * 8 + q * 2);
    const float4 sv = scl[bt];

    int a0 = 0, a1 = 0, a2 = 0, a3 = 0, am = 0, ae = 0;
    a0 = dot4(wx[0].x, X.x, a0); a0 = dot4(wx[0].y, X.y, a0);
    a0 = dot4(wx[0].z, X.z, a0); a0 = dot4(wx[0].w, X.w, a0);
    a1 = dot4(wx[1].x, X.x, a1); a1 = dot4(wx[1].y, X.y, a1);
    a1 = dot4(wx[1].z, X.z, a1); a1 = dot4(wx[1].w, X.w, a1);
    a2 = dot4(wx[2].x, X.x, a2); a2 = dot4(wx[2].y, X.y, a2);
    a2 = dot4(wx[2].z, X.z, a2); a2 = dot4(wx[2].w, X.w, a2);
    a3 = dot4(wx[3].x, X.x, a3); a3 = dot4(wx[3].y, X.y, a3);
    a3 = dot4(wx[3].z, X.z, a3); a3 = dot4(wx[3].w, X.w, a3);
    am = dot4(wmv.x, X.x, am);   am = dot4(wmv.y, X.y, am);
    am = dot4(wmv.z, X.z, am);   am = dot4(wmv.w, X.w, am);
    ae = dot4(wev.x, E.x, ae);   ae = dot4(wev.y, E.y, ae);

    a0 = qsum(a0); a1 = qsum(a1); a2 = qsum(a2);
    a3 = qsum(a3); am = qsum(am); ae = qsum(ae);

    if (q == 0) {
      const float fx = sXF * sv.x;
      const float p0 = (float)a0 * fx + bf[0];
      const float p1 = (float)a1 * fx + bf[1];
      const float p2 = (float)a2 * fx + bf[2];
      const float p3 = (float)a3 * fx + bf[3];
      const float mkS = sigm((float)am * (sMK * sv.x) + bmkv);
      const float EF = tanh_f((float)ae * (sE * sv.y) + bev) * sv.z;
      uint4 o;
      o.x = pkh(p0, p1);
      o.y = pkh(p2, p3);
      o.z = __float_as_uint(mkS);
      o.w = __float_as_uint(EF);
      pre[(size_t)idx * 256 + j] = o;
    }
  }
}

// ---------- the scan: all weights reg-resident; LDS = 512 B of h only ----------
__global__ __launch_bounds__(1024) void scan3(
    int t0, int steps, const uint* __restrict__ WhQ,
    const float* __restrict__ scales, const float* __restrict__ bhg,
    const uint4* __restrict__ pre, uchar* __restrict__ hB, float* __restrict__ cB,
    float* __restrict__ feat) {
  __shared__ __align__(16) uint hqW[128];  // double-buffered int8 h (512 B)
  const int tid = threadIdx.x, b = blockIdx.x;
  const int j = tid >> 2, q = tid & 3;

  // ifgo + hg h-weights, this thread's K-quarter: 20 uint4 = 80 regs (VGPR/AGPR)
  const uint4* wv = (const uint4*)WhQ;
  uint4 wh[4][4];
#pragma unroll
  for (int g = 0; g < 4; ++g)
#pragma unroll
    for (int m = 0; m < 4; ++m) wh[g][m] = wv[((g * 256 + j) * 4 + q) * 4 + m];
  uint4 wg[4];
#pragma unroll
  for (int m = 0; m < 4; ++m) wg[m] = wv[((1024 + j) * 4 + q) * 4 + m];

  float c;
  if (t0 == 0) {
    c = 0.0f;
    if (tid < 64) hqW[tid] = 0u;
  } else {
    c = cB[b * 256 + j];
    if (tid < 64) hqW[tid] = ((const uint*)hB)[b * 64 + tid];
  }
  const float kHH = scales[0] * (1.0f / 127.0f);
  const float kHG = scales[1] * (1.0f / 127.0f);
  const float bhgv = bhg[j];
  const uint4* prep = pre + (size_t)b * steps * 256;
  float* fout = feat + ((size_t)b * TT + t0) * HH;
  int buf = 0;
  __syncthreads();

  uint4 P = prep[j];  // t=0 preacts
  for (int t = 0; t < steps; ++t) {
    uint4 Pn = P;
    if (t + 1 < steps) Pn = prep[(size_t)(t + 1) * 256 + j];  // prefetch next step

    int a0 = 0, a1 = 0, a2 = 0, a3 = 0, a4 = 0;
    const uint4* hp = (const uint4*)((const uchar*)hqW + buf * 256 + q * 64);
#pragma unroll
    for (int m = 0; m < 4; ++m) {
      const uint4 hv = hp[m];
      a0 = dot4(wh[0][m].x, hv.x, a0); a0 = dot4(wh[0][m].y, hv.y, a0);
      a0 = dot4(wh[0][m].z, hv.z, a0); a0 = dot4(wh[0][m].w, hv.w, a0);
      a1 = dot4(wh[1][m].x, hv.x, a1); a1 = dot4(wh[1][m].y, hv.y, a1);
      a1 = dot4(wh[1][m].z, hv.z, a1); a1 = dot4(wh[1][m].w, hv.w, a1);
      a2 = dot4(wh[2][m].x, hv.x, a2); a2 = dot4(wh[2][m].y, hv.y, a2);
      a2 = dot4(wh[2][m].z, hv.z, a2); a2 = dot4(wh[2][m].w, hv.w, a2);
      a3 = dot4(wh[3][m].x, hv.x, a3); a3 = dot4(wh[3][m].y, hv.y, a3);
      a3 = dot4(wh[3][m].z, hv.z, a3); a3 = dot4(wh[3][m].w, hv.w, a3);
      a4 = dot4(wg[m].x, hv.x, a4);    a4 = dot4(wg[m].y, hv.y, a4);
      a4 = dot4(wg[m].z, hv.z, a4);    a4 = dot4(wg[m].w, hv.w, a4);
    }
    a0 = qsum(a0); a1 = qsum(a1); a2 = qsum(a2); a3 = qsum(a3); a4 = qsum(a4);

    const half2v pif = uph(P.x), pgo = uph(P.y);
    const float p0 = (float)a0 * kHH + (float)pif.x;
    const float p1 = (float)a1 * kHH + (float)pif.y;
    const float p2 = (float)a2 * kHH + (float)pgo.x;
    const float p3 = (float)a3 * kHH + (float)pgo.y;
    const float p4 = (float)a4 * kHG + bhgv;
    const float mkS = __uint_as_float(P.z);
    const float EF = __uint_as_float(P.w);

    const float impact = EF * sigm(p4);
    c = sigm(p1) * c + sigm(p0) * tanh_f(p2) + mkS * tanh_f(impact);
    const float hn = sigm(p3) * tanh_f(c);

    if (q == 0) {
      fout[(size_t)t * HH + j] = hn;
      int qi = __float2int_rn(hn * 127.0f);
      ((uchar*)hqW)[(buf ^ 1) * 256 + j] = (uchar)(qi & 0xff);
    }
    __syncthreads();
    buf ^= 1;
    P = Pn;
  }
  if (q == 0) cB[b * 256 + j] = c;
  if (tid < 64) ((uint*)hB)[b * 64 + tid] = hqW[buf * 64 + tid];
}

// ---------- predictor: f16 pairs + v_dot2; 128 rows/block; thread=(j, K-half) ----------
__global__ __launch_bounds__(256) void pred3(
    const float* __restrict__ feat, const uint* __restrict__ WQh,
    const float* __restrict__ bp1, const float* __restrict__ Wp2,
    const float* __restrict__ bp2, float* __restrict__ out0) {
  __shared__ uint WL[16384];       // W1 f16-pairs [j][kp] (64 KB)
  __shared__ uint hT[128 * 132];   // h f16-pairs [row][kp], padded stride (67.6 KB)
  __shared__ float psum[4][128];

  const int tid = threadIdx.x, w = tid >> 6, l = tid & 63;
  const int rbase = blockIdx.x * 128;

  for (int i = tid; i < 16384; i += 256) WL[i] = WQh[i];
  for (int i = tid; i < 16384; i += 256) {
    int row = i >> 7, kp = i & 127;
    const float2 hv = ((const float2*)feat)[(size_t)(rbase + row) * 128 + kp];
    hT[row * 132 + kp] = pkh(hv.x, hv.y);
  }
  __syncthreads();

  float ma[32], mb[32];
#pragma unroll
  for (int jj = 0; jj < 32; ++jj) {
    const float bv = bp1[w * 32 + jj];
    ma[jj] = bv;
    mb[jj] = bv;
  }
  const uint* ha = &hT[l * 132];
  const uint* hb = &hT[(l + 64) * 132];
  const uint* wbase = &WL[(w * 32) * 128];
  for (int kp4 = 0; kp4 < 32; ++kp4) {
    const uint4 a4 = *(const uint4*)&ha[kp4 * 4];
    const uint4 b4 = *(const uint4*)&hb[kp4 * 4];
#pragma unroll
    for (int jj = 0; jj < 32; ++jj) {
      const uint4 w4 = *(const uint4*)&wbase[jj * 128 + kp4 * 4];
      ma[jj] = fdot2u(w4.x, a4.x, ma[jj]);
      ma[jj] = fdot2u(w4.y, a4.y, ma[jj]);
      ma[jj] = fdot2u(w4.z, a4.z, ma[jj]);
      ma[jj] = fdot2u(w4.w, a4.w, ma[jj]);
      mb[jj] = fdot2u(w4.x, b4.x, mb[jj]);
      mb[jj] = fdot2u(w4.y, b4.y, mb[jj]);
      mb[jj] = fdot2u(w4.z, b4.z, mb[jj]);
      mb[jj] = fdot2u(w4.w, b4.w, mb[jj]);
    }
  }
  float accA = 0.f, accB = 0.f;
#pragma unroll
  for (int jj = 0; jj < 32; ++jj) {
    const float w2v = Wp2[w * 32 + jj];
    accA += 0.5f * ma[jj] * (1.0f + erff(ma[jj] * 0.70710678118f)) * w2v;
    accB += 0.5f * mb[jj] * (1.0f + erff(mb[jj] * 0.70710678118f)) * w2v;
  }
  psum[w][l] = accA;
  psum[w][64 + l] = accB;
  __syncthreads();
  if (tid < 128)
    out0[rbase + tid] =
        psum[0][tid] + psum[1][tid] + psum[2][tid] + psum[3][tid] + bp2[0];
}

extern "C" void kernel_launch(void* const* d_in, const int* in_sizes, int n_in,
                              void* d_out, int out_size, void* d_ws, size_t ws_size,
                              hipStream_t stream) {
  const float* x = (const float*)d_in[0];
  const float* ev = (const float*)d_in[1];
  const float* td = (const float*)d_in[2];
  const float* Wproj = (const float*)d_in[3];
  const float* bproj = (const float*)d_in[4];
  const float* Wih = (const float*)d_in[5];
  const float* Whh = (const float*)d_in[6];
  const float* blstm = (const float*)d_in[7];
  const float* Wmk = (const float*)d_in[8];
  const float* bmk = (const float*)d_in[9];
  const float* We = (const float*)d_in[10];
  const float* be = (const float*)d_in[11];
  const float* Whg = (const float*)d_in[12];
  const float* bhg = (const float*)d_in[13];
  const float* decay = (const float*)d_in[14];
  const float* Wp1 = (const float*)d_in[15];
  const float* bp1 = (const float*)d_in[16];
  const float* Wp2 = (const float*)d_in[17];
  const float* bp2 = (const float*)d_in[18];

  float* out0 = (float*)d_out;                // predictions [B,T,1]
  float* out1 = out0 + (size_t)BT;            // features    [B,T,H]
  float* out2 = out1 + (size_t)BT * HH;       // tmdo d1     [B,T,64]

  char* w = (char*)d_ws;
  float* Wfold_f = (float*)w; w += (size_t)65536 * 4;   // 256 KB
  uint* WhQ = (uint*)w; w += (size_t)81920 * 4;         // 320 KB (Whh ifgo + Whg)
  uint* XQ = (uint*)w; w += (size_t)20480 * 4;          // 80 KB
  uint* EQ = (uint*)w; w += (size_t)2048 * 4;           // 8 KB
  uint* WQh = (uint*)w; w += (size_t)16384 * 4;         // 64 KB
  float* scales = (float*)w; w += 16 * 4;
  float* bfold = (float*)w; w += 1024 * 4;
  uchar* hB = (uchar*)w; w += (size_t)BB * 256;         // 32 KB int8 h state
  float* cB = (float*)w; w += (size_t)BB * 256 * 4;     // 128 KB c state
  uint* xq = (uint*)w; w += (size_t)BT * 16 * 4;        // 8 MB
  uint* eq = (uint*)w; w += (size_t)BT * 8 * 4;         // 4 MB
  float4* scl = (float4*)w; w += (size_t)BT * 16;       // 2 MB
  uint4* pre = (uint4*)w;                               // remainder: x-preacts

  // size the T-chunk from remaining workspace (pre = 128*steps*256*16 B per chunk)
  size_t used = (size_t)(w - (char*)d_ws);
  size_t avail = (ws_size > used + 4096) ? (ws_size - used - 4096) : 0;
  int steps = TT, lsteps = 10;
  while (steps > 4 && (size_t)BB * (size_t)steps * 256 * 16 > avail) {
    steps >>= 1;
    lsteps--;
  }

  hipLaunchKernelGGL(fold_f32, dim3(256), dim3(256), 0, stream, Wproj, Wih, Wfold_f);
  hipLaunchKernelGGL(bfold_kernel, dim3(4), dim3(256), 0, stream, bproj, Wih, blstm, bfold);
  hipLaunchKernelGGL(quant_all, dim3(5), dim3(1024), 0, stream,
                     Whh, Whg, Wfold_f, Wmk, We, WhQ, XQ, EQ, scales);
  hipLaunchKernelGGL(pack_wp1h, dim3(64), dim3(256), 0, stream, Wp1, WQh);
  hipLaunchKernelGGL(prep_inputs, dim3(BT / 4), dim3(256), 0, stream,
                     x, ev, td, decay, xq, eq, scl);
  hipLaunchKernelGGL(d1_kernel, dim3(8192), dim3(256), 0, stream, x, out2);

  for (int t0 = 0; t0 < TT; t0 += steps) {
    hipLaunchKernelGGL(pre2, dim3(2 * steps), dim3(1024), 0, stream,
                       t0, lsteps, XQ, EQ, scales, bfold, bmk, be, xq, eq, scl, pre);
    hipLaunchKernelGGL(scan3, dim3(BB), dim3(1024), 0, stream,
                       t0, steps, WhQ, scales, bhg, pre, hB, cB, out1);
  }

  hipLaunchKernelGGL(pred3, dim3(BT / 128), dim3(256), 0, stream,
                     out1, WQh, bp1, Wp2, bp2, out0);
}

// Round 9
// 1903.252 us; speedup vs baseline: 1.1108x; 1.1108x over previous
//
#include <hip/hip_runtime.h>
#include <hip/hip_bf16.h>
#include <hip/hip_fp16.h>
#include <math.h>

#define BB 128
#define TT 1024
#define DIN 64
#define HH 256
#define EE 32
#define BT (BB * TT)

typedef unsigned int uint;
typedef unsigned char uchar;
typedef _Float16 half2v __attribute__((ext_vector_type(2)));

__device__ __forceinline__ int dot4(uint a, uint b, int c) {
  return __builtin_amdgcn_sdot4((int)a, (int)b, c, false);
}
__device__ __forceinline__ uint pkh(float a, float b) {
  return __builtin_bit_cast(uint, __builtin_amdgcn_cvt_pkrtz(a, b));
}
__device__ __forceinline__ half2v uph(uint u) { return __builtin_bit_cast(half2v, u); }
__device__ __forceinline__ float fdot2u(uint a, uint b, float c) {
  return __builtin_amdgcn_fdot2(uph(a), uph(b), c, false);
}
#define IDPP(v, c) __builtin_amdgcn_mov_dpp((v), (c), 0xF, 0xF, true)
__device__ __forceinline__ int qsum(int v) {  // quad butterfly sum (VALU only)
  v += IDPP(v, 0xB1);  // xor 1
  v += IDPP(v, 0x4E);  // xor 2
  return v;
}
__device__ __forceinline__ float rcp_f(float x) { return __builtin_amdgcn_rcpf(x); }
__device__ __forceinline__ float sigm(float x) { return rcp_f(1.0f + __expf(-x)); }
__device__ __forceinline__ float tanh_f(float x) {
  return 1.0f - 2.0f * rcp_f(__expf(2.0f * x) + 1.0f);
}

// ---------- Wfold = W_proj @ W_ih (fp32) ----------
__global__ void fold_f32(const float* __restrict__ Wproj, const float* __restrict__ Wih,
                         float* __restrict__ Wfold) {
  int idx = blockIdx.x * blockDim.x + threadIdx.x;
  if (idx >= 64 * 1024) return;
  int d = idx >> 10, n = idx & 1023;
  float a = 0.f;
  for (int k = 0; k < 256; ++k) a += Wproj[d * 256 + k] * Wih[k * 1024 + n];
  Wfold[d * 1024 + n] = a;
}

// bfold[n] = b_proj @ W_ih + b_lstm
__global__ void bfold_kernel(const float* __restrict__ bproj, const float* __restrict__ Wih,
                             const float* __restrict__ blstm, float* __restrict__ bfold) {
  int n = blockIdx.x * blockDim.x + threadIdx.x;
  if (n >= 1024) return;
  float a = blstm[n];
  for (int k = 0; k < 256; ++k) a += bproj[k] * Wih[k * 1024 + n];
  bfold[n] = a;
}

// ---------- quantize weights, per-matrix scales ----------
// WhQ (scan, reg-resident): col-major-K: WhQ[c*64 + k4], c<1024 = Whh col (ifgo),
//   c in [1024,1280) = Whg col; k = 4*k4 + bb.
// XQ (pre): uint idx c*16 + k4; c<1024 Wfold col, else Wmk col (K=64).
// EQ (pre): uint idx c*8 + k4 (K=32).
__global__ __launch_bounds__(1024) void quant_all(
    const float* __restrict__ Whh, const float* __restrict__ Whg,
    const float* __restrict__ Wfold, const float* __restrict__ Wmk,
    const float* __restrict__ We,
    uint* __restrict__ WhQ, uint* __restrict__ XQ, uint* __restrict__ EQ,
    float* __restrict__ scales) {
  const int bid = blockIdx.x, tid = threadIdx.x;
  const float* src;
  int nelem;
  switch (bid) {
    case 0: src = Whh;   nelem = 262144; break;
    case 1: src = Whg;   nelem = 65536;  break;
    case 2: src = Wfold; nelem = 65536;  break;
    case 3: src = Wmk;   nelem = 16384;  break;
    default: src = We;   nelem = 8192;   break;
  }
  float m = 0.f;
  for (int i = tid; i < nelem; i += 1024) m = fmaxf(m, fabsf(src[i]));
#pragma unroll
  for (int d = 1; d < 64; d <<= 1) m = fmaxf(m, __shfl_xor(m, d));
  __shared__ float wm[16];
  if ((tid & 63) == 0) wm[tid >> 6] = m;
  __syncthreads();
  float mg = wm[0];
#pragma unroll
  for (int i = 1; i < 16; ++i) mg = fmaxf(mg, wm[i]);
  mg = fmaxf(mg, 1e-8f);
  if (tid == 0) scales[bid] = mg * (1.0f / 127.0f);
  const float inv = 127.0f / mg;

  if (bid == 0) {  // Whh -> WhQ[0..65536): c = i>>6, k4 = i&63
    for (int i = tid; i < 65536; i += 1024) {
      int c = i >> 6, k4 = i & 63;
      uint d = 0;
#pragma unroll
      for (int bb = 0; bb < 4; ++bb) {
        int qv = __float2int_rn(Whh[(4 * k4 + bb) * 1024 + c] * inv);
        qv = max(-127, min(127, qv));
        d |= ((uint)(qv & 0xff)) << (8 * bb);
      }
      WhQ[i] = d;
    }
  } else if (bid == 1) {  // Whg -> WhQ[65536..81920): j = i>>6, k4 = i&63
    for (int i = tid; i < 16384; i += 1024) {
      int j = i >> 6, k4 = i & 63;
      uint d = 0;
#pragma unroll
      for (int bb = 0; bb < 4; ++bb) {
        int qv = __float2int_rn(Whg[(4 * k4 + bb) * 256 + j] * inv);
        qv = max(-127, min(127, qv));
        d |= ((uint)(qv & 0xff)) << (8 * bb);
      }
      WhQ[65536 + i] = d;
    }
  } else if (bid == 2) {  // Wfold -> XQ[0..16384)
    for (int i = tid; i < 16384; i += 1024) {
      int c = i >> 4, k4 = i & 15;
      uint d = 0;
#pragma unroll
      for (int bb = 0; bb < 4; ++bb) {
        int qv = __float2int_rn(Wfold[(4 * k4 + bb) * 1024 + c] * inv);
        qv = max(-127, min(127, qv));
        d |= ((uint)(qv & 0xff)) << (8 * bb);
      }
      XQ[i] = d;
    }
  } else if (bid == 3) {  // Wmk -> XQ[16384..20480)
    for (int i = tid; i < 4096; i += 1024) {
      int j = i >> 4, k4 = i & 15;
      uint d = 0;
#pragma unroll
      for (int bb = 0; bb < 4; ++bb) {
        int qv = __float2int_rn(Wmk[(4 * k4 + bb) * 256 + j] * inv);
        qv = max(-127, min(127, qv));
        d |= ((uint)(qv & 0xff)) << (8 * bb);
      }
      XQ[16384 + i] = d;
    }
  } else {  // We -> EQ[0..2048)
    for (int i = tid; i < 2048; i += 1024) {
      int c = i >> 3, k4 = i & 7;
      uint d = 0;
#pragma unroll
      for (int bb = 0; bb < 4; ++bb) {
        int qv = __float2int_rn(We[(4 * k4 + bb) * 256 + c] * inv);
        qv = max(-127, min(127, qv));
        d |= ((uint)(qv & 0xff)) << (8 * bb);
      }
      EQ[i] = d;
    }
  }
}

// ---------- pack Wp1 [256][128] -> f16 k-pairs: WQ[j*128 + kp] ----------
__global__ void pack_wp1h(const float* __restrict__ Wp1, uint* __restrict__ WQ) {
  int idx = blockIdx.x * blockDim.x + threadIdx.x;
  if (idx >= 16384) return;
  int j = idx >> 7, kp = idx & 127;
  WQ[idx] = pkh(Wp1[(2 * kp) * 128 + j], Wp1[(2 * kp + 1) * 128 + j]);
}

// ---------- per-(b,t) input quantization + scl={xsc,esc,fac,0} ----------
__global__ __launch_bounds__(256) void prep_inputs(
    const float* __restrict__ x, const float* __restrict__ ev, const float* __restrict__ td,
    const float* __restrict__ decay, uint* __restrict__ xq, uint* __restrict__ eq,
    float4* __restrict__ scl) {
  int wid = threadIdx.x >> 6, lane = threadIdx.x & 63;
  int bt = blockIdx.x * 4 + wid;
  if (bt >= BT) return;
  float xv = x[(size_t)bt * DIN + lane];
  float evv = (lane < EE) ? ev[(size_t)bt * EE + lane] : 0.0f;
  float ax = fabsf(xv), ae = fabsf(evv);
#pragma unroll
  for (int m = 1; m < 64; m <<= 1) {
    ax = fmaxf(ax, __shfl_xor(ax, m));
    ae = fmaxf(ae, __shfl_xor(ae, m));
  }
  float mgx = fmaxf(ax, 1e-8f), mge = fmaxf(ae, 1e-8f);
  int qx = __float2int_rn(xv * (127.0f / mgx));
  qx = max(-127, min(127, qx));
  int qe = __float2int_rn(evv * (127.0f / mge));
  qe = max(-127, min(127, qe));
  uint dx = 0, de = 0;
#pragma unroll
  for (int b = 0; b < 4; ++b) dx |= ((uint)(__shfl(qx, lane * 4 + b) & 0xff)) << (8 * b);
#pragma unroll
  for (int b = 0; b < 4; ++b) de |= ((uint)(__shfl(qe, lane * 4 + b) & 0xff)) << (8 * b);
  if (lane < 16) xq[(size_t)bt * 16 + lane] = dx;
  if (lane < 8) eq[(size_t)bt * 8 + lane] = de;
  if (lane == 0) {
    float sp = log1pf(__expf(decay[0]));
    scl[bt] = make_float4(mgx * (1.0f / 127.0f), mge * (1.0f / 127.0f),
                          __expf(-sp * td[bt]), 0.0f);
  }
}

// ---------- output 2: first temporal difference ----------
__global__ void d1_kernel(const float* __restrict__ x, float* __restrict__ out2) {
  int idx = blockIdx.x * blockDim.x + threadIdx.x;
  const int per_t = DIN / 4;
  if (idx >= BB * TT * per_t) return;
  int t = (idx / per_t) % TT;
  float4 cur = reinterpret_cast<const float4*>(x)[idx];
  float4 res;
  if (t == 0) {
    res = make_float4(0.f, 0.f, 0.f, 0.f);
  } else {
    float4 prv = reinterpret_cast<const float4*>(x)[idx - per_t];
    res = make_float4(cur.x - prv.x, cur.y - prv.y, cur.z - prv.z, cur.w - prv.w);
  }
  reinterpret_cast<float4*>(out2)[idx] = res;
}

// ---------- precompute x/e-side per (bt, j): preA={f16 ifgo+bias}, preB={mkS,EF} f16 ----------
// 1024 thr = 256 j x 4 K-quarters q; DPP quad-reduce; lane q=0 stores.
__global__ __launch_bounds__(1024) void pre2(
    int t0, int lsteps,
    const uint* __restrict__ XQ, const uint* __restrict__ EQ,
    const float* __restrict__ scales, const float* __restrict__ bfold,
    const float* __restrict__ bmk, const float* __restrict__ be,
    const uint* __restrict__ xq, const uint* __restrict__ eqp,
    const float4* __restrict__ scl,
    uint2* __restrict__ preA, uint* __restrict__ preB) {
  const int tid = threadIdx.x;
  const int j = tid >> 2, q = tid & 3;

  uint4 wx[4];
#pragma unroll
  for (int g = 0; g < 4; ++g)
    wx[g] = *(const uint4*)(XQ + (g * 256 + j) * 16 + q * 4);
  const uint4 wmv = *(const uint4*)(XQ + 16384 + j * 16 + q * 4);
  const uint2 wev = *(const uint2*)(EQ + j * 8 + q * 2);
  float bf[4];
#pragma unroll
  for (int g = 0; g < 4; ++g) bf[g] = bfold[g * 256 + j];
  const float bmkv = bmk[j], bev = be[j];
  const float sXF = scales[2], sMK = scales[3], sE = scales[4];
  const int steps = 1 << lsteps;

  for (int it = 0; it < 64; ++it) {
    const int idx = blockIdx.x * 64 + it;
    const int b = idx >> lsteps, tl = idx & (steps - 1);
    const int bt = b * TT + t0 + tl;
    const uint4 X = *(const uint4*)(xq + (size_t)bt * 16 + q * 4);
    const uint2 E = *(const uint2*)(eqp + (size_t)bt * 8 + q * 2);
    const float4 sv = scl[bt];

    int a0 = 0, a1 = 0, a2 = 0, a3 = 0, am = 0, ae = 0;
    a0 = dot4(wx[0].x, X.x, a0); a0 = dot4(wx[0].y, X.y, a0);
    a0 = dot4(wx[0].z, X.z, a0); a0 = dot4(wx[0].w, X.w, a0);
    a1 = dot4(wx[1].x, X.x, a1); a1 = dot4(wx[1].y, X.y, a1);
    a1 = dot4(wx[1].z, X.z, a1); a1 = dot4(wx[1].w, X.w, a1);
    a2 = dot4(wx[2].x, X.x, a2); a2 = dot4(wx[2].y, X.y, a2);
    a2 = dot4(wx[2].z, X.z, a2); a2 = dot4(wx[2].w, X.w, a2);
    a3 = dot4(wx[3].x, X.x, a3); a3 = dot4(wx[3].y, X.y, a3);
    a3 = dot4(wx[3].z, X.z, a3); a3 = dot4(wx[3].w, X.w, a3);
    am = dot4(wmv.x, X.x, am);   am = dot4(wmv.y, X.y, am);
    am = dot4(wmv.z, X.z, am);   am = dot4(wmv.w, X.w, am);
    ae = dot4(wev.x, E.x, ae);   ae = dot4(wev.y, E.y, ae);

    a0 = qsum(a0); a1 = qsum(a1); a2 = qsum(a2);
    a3 = qsum(a3); am = qsum(am); ae = qsum(ae);

    if (q == 0) {
      const float fx = sXF * sv.x;
      const float p0 = (float)a0 * fx + bf[0];
      const float p1 = (float)a1 * fx + bf[1];
      const float p2 = (float)a2 * fx + bf[2];
      const float p3 = (float)a3 * fx + bf[3];
      const float mkS = sigm((float)am * (sMK * sv.x) + bmkv);
      const float EF = tanh_f((float)ae * (sE * sv.y) + bev) * sv.z;
      preA[(size_t)idx * 256 + j] = make_uint2(pkh(p0, p1), pkh(p2, p3));
      preB[(size_t)idx * 256 + j] = pkh(mkS, EF);
    }
  }
}

// ---------- the scan: 512 thr = (j, K-half); weights 160 uints reg-resident ----------
__attribute__((amdgpu_waves_per_eu(2, 2)))
__global__ __launch_bounds__(512, 2) void scan4(
    int t0, int steps, const uint* __restrict__ WhQ,
    const float* __restrict__ scales, const float* __restrict__ bhg,
    const uint2* __restrict__ preA, const uint* __restrict__ preB,
    uchar* __restrict__ hB, float* __restrict__ cB, float* __restrict__ feat) {
  __shared__ __align__(16) uint hqW[128];  // double-buffered int8 h (512 B)
  const int tid = threadIdx.x, b = blockIdx.x;
  const int j = tid >> 1, kh = tid & 1;

  // 5 gates x 8 uint4 (this thread's K-half) = 160 regs
  const uint4* wv = (const uint4*)WhQ;
  uint4 wh[4][8];
#pragma unroll
  for (int g = 0; g < 4; ++g)
#pragma unroll
    for (int m = 0; m < 8; ++m) wh[g][m] = wv[(g * 256 + j) * 16 + kh * 8 + m];
  uint4 wg[8];
#pragma unroll
  for (int m = 0; m < 8; ++m) wg[m] = wv[(1024 + j) * 16 + kh * 8 + m];

  float c;
  if (t0 == 0) {
    c = 0.0f;
    if (tid < 64) hqW[tid] = 0u;
  } else {
    c = cB[b * 256 + j];
    if (tid < 64) hqW[tid] = ((const uint*)hB)[b * 64 + tid];
  }
  const float kHH = scales[0] * (1.0f / 127.0f);
  const float kHG = scales[1] * (1.0f / 127.0f);
  const float bhgv = bhg[j];
  const uint2* pA = preA + (size_t)b * steps * 256;
  const uint* pB = preB + (size_t)b * steps * 256;
  float* fout = feat + ((size_t)b * TT + t0) * HH;
  int buf = 0;
  __syncthreads();

  uint2 PA = pA[j];
  uint PB = pB[j];
#pragma unroll 2
  for (int t = 0; t < steps; ++t) {
    // prefetch next step's records (safe over-read into following ws region)
    const uint2 PAn = pA[(size_t)(t + 1) * 256 + j];
    const uint PBn = pB[(size_t)(t + 1) * 256 + j];

    int a0 = 0, a1 = 0, a2 = 0, a3 = 0, a4 = 0;
    const uint4* hp = (const uint4*)((const uchar*)hqW + buf * 256 + kh * 128);
#pragma unroll
    for (int m = 0; m < 8; ++m) {
      const uint4 hv = hp[m];
      a0 = dot4(wh[0][m].x, hv.x, a0); a0 = dot4(wh[0][m].y, hv.y, a0);
      a0 = dot4(wh[0][m].z, hv.z, a0); a0 = dot4(wh[0][m].w, hv.w, a0);
      a1 = dot4(wh[1][m].x, hv.x, a1); a1 = dot4(wh[1][m].y, hv.y, a1);
      a1 = dot4(wh[1][m].z, hv.z, a1); a1 = dot4(wh[1][m].w, hv.w, a1);
      a2 = dot4(wh[2][m].x, hv.x, a2); a2 = dot4(wh[2][m].y, hv.y, a2);
      a2 = dot4(wh[2][m].z, hv.z, a2); a2 = dot4(wh[2][m].w, hv.w, a2);
      a3 = dot4(wh[3][m].x, hv.x, a3); a3 = dot4(wh[3][m].y, hv.y, a3);
      a3 = dot4(wh[3][m].z, hv.z, a3); a3 = dot4(wh[3][m].w, hv.w, a3);
      a4 = dot4(wg[m].x, hv.x, a4);    a4 = dot4(wg[m].y, hv.y, a4);
      a4 = dot4(wg[m].z, hv.z, a4);    a4 = dot4(wg[m].w, hv.w, a4);
    }
    // pair reduce (lane 2j <-> 2j+1)
    a0 += __shfl_xor(a0, 1);
    a1 += __shfl_xor(a1, 1);
    a2 += __shfl_xor(a2, 1);
    a3 += __shfl_xor(a3, 1);
    a4 += __shfl_xor(a4, 1);

    const half2v pif = uph(PA.x), pgo = uph(PA.y), mkEF = uph(PB);
    const float p0 = (float)a0 * kHH + (float)pif.x;
    const float p1 = (float)a1 * kHH + (float)pif.y;
    const float p2 = (float)a2 * kHH + (float)pgo.x;
    const float p3 = (float)a3 * kHH + (float)pgo.y;
    const float p4 = (float)a4 * kHG + bhgv;
    const float mkS = (float)mkEF.x;
    const float EF = (float)mkEF.y;

    const float impact = EF * sigm(p4);
    c = sigm(p1) * c + sigm(p0) * tanh_f(p2) + mkS * tanh_f(impact);
    const float hn = sigm(p3) * tanh_f(c);

    if (kh == 0) {
      fout[(size_t)t * HH + j] = hn;
      int qi = __float2int_rn(hn * 127.0f);
      ((uchar*)hqW)[(buf ^ 1) * 256 + j] = (uchar)(qi & 0xff);
    }
    __syncthreads();
    buf ^= 1;
    PA = PAn;
    PB = PBn;
  }
  if (kh == 0) cB[b * 256 + j] = c;
  if (tid < 64) ((uint*)hB)[b * 64 + tid] = hqW[buf * 64 + tid];
}

// ---------- predictor: f16 pairs + v_dot2; 128 rows/block; thread=(j, K-half) ----------
__global__ __launch_bounds__(256) void pred3(
    const float* __restrict__ feat, const uint* __restrict__ WQh,
    const float* __restrict__ bp1, const float* __restrict__ Wp2,
    const float* __restrict__ bp2, float* __restrict__ out0) {
  __shared__ uint WL[16384];       // W1 f16-pairs [j][kp] (64 KB)
  __shared__ uint hT[128 * 132];   // h f16-pairs [row][kp], padded stride (67.6 KB)
  __shared__ float psum[4][128];

  const int tid = threadIdx.x, w = tid >> 6, l = tid & 63;
  const int rbase = blockIdx.x * 128;

  for (int i = tid; i < 16384; i += 256) WL[i] = WQh[i];
  for (int i = tid; i < 16384; i += 256) {
    int row = i >> 7, kp = i & 127;
    const float2 hv = ((const float2*)feat)[(size_t)(rbase + row) * 128 + kp];
    hT[row * 132 + kp] = pkh(hv.x, hv.y);
  }
  __syncthreads();

  float ma[32], mb[32];
#pragma unroll
  for (int jj = 0; jj < 32; ++jj) {
    const float bv = bp1[w * 32 + jj];
    ma[jj] = bv;
    mb[jj] = bv;
  }
  const uint* ha = &hT[l * 132];
  const uint* hb = &hT[(l + 64) * 132];
  const uint* wbase = &WL[(w * 32) * 128];
  for (int kp4 = 0; kp4 < 32; ++kp4) {
    const uint4 a4 = *(const uint4*)&ha[kp4 * 4];
    const uint4 b4 = *(const uint4*)&hb[kp4 * 4];
#pragma unroll
    for (int jj = 0; jj < 32; ++jj) {
      const uint4 w4 = *(const uint4*)&wbase[jj * 128 + kp4 * 4];
      ma[jj] = fdot2u(w4.x, a4.x, ma[jj]);
      ma[jj] = fdot2u(w4.y, a4.y, ma[jj]);
      ma[jj] = fdot2u(w4.z, a4.z, ma[jj]);
      ma[jj] = fdot2u(w4.w, a4.w, ma[jj]);
      mb[jj] = fdot2u(w4.x, b4.x, mb[jj]);
      mb[jj] = fdot2u(w4.y, b4.y, mb[jj]);
      mb[jj] = fdot2u(w4.z, b4.z, mb[jj]);
      mb[jj] = fdot2u(w4.w, b4.w, mb[jj]);
    }
  }
  float accA = 0.f, accB = 0.f;
#pragma unroll
  for (int jj = 0; jj < 32; ++jj) {
    const float w2v = Wp2[w * 32 + jj];
    accA += 0.5f * ma[jj] * (1.0f + erff(ma[jj] * 0.70710678118f)) * w2v;
    accB += 0.5f * mb[jj] * (1.0f + erff(mb[jj] * 0.70710678118f)) * w2v;
  }
  psum[w][l] = accA;
  psum[w][64 + l] = accB;
  __syncthreads();
  if (tid < 128)
    out0[rbase + tid] =
        psum[0][tid] + psum[1][tid] + psum[2][tid] + psum[3][tid] + bp2[0];
}

extern "C" void kernel_launch(void* const* d_in, const int* in_sizes, int n_in,
                              void* d_out, int out_size, void* d_ws, size_t ws_size,
                              hipStream_t stream) {
  const float* x = (const float*)d_in[0];
  const float* ev = (const float*)d_in[1];
  const float* td = (const float*)d_in[2];
  const float* Wproj = (const float*)d_in[3];
  const float* bproj = (const float*)d_in[4];
  const float* Wih = (const float*)d_in[5];
  const float* Whh = (const float*)d_in[6];
  const float* blstm = (const float*)d_in[7];
  const float* Wmk = (const float*)d_in[8];
  const float* bmk = (const float*)d_in[9];
  const float* We = (const float*)d_in[10];
  const float* be = (const float*)d_in[11];
  const float* Whg = (const float*)d_in[12];
  const float* bhg = (const float*)d_in[13];
  const float* decay = (const float*)d_in[14];
  const float* Wp1 = (const float*)d_in[15];
  const float* bp1 = (const float*)d_in[16];
  const float* Wp2 = (const float*)d_in[17];
  const float* bp2 = (const float*)d_in[18];

  float* out0 = (float*)d_out;                // predictions [B,T,1]
  float* out1 = out0 + (size_t)BT;            // features    [B,T,H]
  float* out2 = out1 + (size_t)BT * HH;       // tmdo d1     [B,T,64]

  char* w = (char*)d_ws;
  float* Wfold_f = (float*)w; w += (size_t)65536 * 4;   // 256 KB
  uint* WhQ = (uint*)w; w += (size_t)81920 * 4;         // 320 KB (Whh ifgo + Whg)
  uint* XQ = (uint*)w; w += (size_t)20480 * 4;          // 80 KB
  uint* EQ = (uint*)w; w += (size_t)2048 * 4;           // 8 KB
  uint* WQh = (uint*)w; w += (size_t)16384 * 4;         // 64 KB
  float* scales = (float*)w; w += 16 * 4;
  float* bfold = (float*)w; w += 1024 * 4;
  uchar* hB = (uchar*)w; w += (size_t)BB * 256;         // 32 KB int8 h state
  float* cB = (float*)w; w += (size_t)BB * 256 * 4;     // 128 KB c state
  uint* xq = (uint*)w; w += (size_t)BT * 16 * 4;        // 8 MB
  uint* eq = (uint*)w; w += (size_t)BT * 8 * 4;         // 4 MB
  float4* scl = (float4*)w; w += (size_t)BT * 16;       // 2 MB

  // size the T-chunk from remaining workspace (preA+preB = 12 B/record)
  size_t used = (size_t)(w - (char*)d_ws);
  size_t avail = (ws_size > used + 8192) ? (ws_size - used - 8192) : 0;
  int steps = TT, lsteps = 10;
  while (steps > 4 && (size_t)BB * (size_t)steps * 256 * 12 > avail) {
    steps >>= 1;
    lsteps--;
  }
  uint2* preA = (uint2*)w; w += (size_t)BB * steps * 256 * 8;
  uint* preB = (uint*)w;

  hipLaunchKernelGGL(fold_f32, dim3(256), dim3(256), 0, stream, Wproj, Wih, Wfold_f);
  hipLaunchKernelGGL(bfold_kernel, dim3(4), dim3(256), 0, stream, bproj, Wih, blstm, bfold);
  hipLaunchKernelGGL(quant_all, dim3(5), dim3(1024), 0, stream,
                     Whh, Whg, Wfold_f, Wmk, We, WhQ, XQ, EQ, scales);
  hipLaunchKernelGGL(pack_wp1h, dim3(64), dim3(256), 0, stream, Wp1, WQh);
  hipLaunchKernelGGL(prep_inputs, dim3(BT / 4), dim3(256), 0, stream,
                     x, ev, td, decay, xq, eq, scl);
  hipLaunchKernelGGL(d1_kernel, dim3(8192), dim3(256), 0, stream, x, out2);

  for (int t0 = 0; t0 < TT; t0 += steps) {
    hipLaunchKernelGGL(pre2, dim3(BB * steps / 64), dim3(1024), 0, stream,
                       t0, lsteps, XQ, EQ, scales, bfold, bmk, be, xq, eq, scl,
                       preA, preB);
    hipLaunchKernelGGL(scan4, dim3(BB), dim3(512), 0, stream,
                       t0, steps, WhQ, scales, bhg, preA, preB, hB, cB, out1);
  }

  hipLaunchKernelGGL(pred3, dim3(BT / 128), dim3(256), 0, stream,
                     out1, WQh, bp1, Wp2, bp2, out0);
}

// Round 10
// 1860.396 us; speedup vs baseline: 1.1364x; 1.0230x over previous
//
#include <hip/hip_runtime.h>
#include <hip/hip_bf16.h>
#include <hip/hip_fp16.h>
#include <math.h>

#define BB 128
#define TT 1024
#define DIN 64
#define HH 256
#define EE 32
#define BT (BB * TT)

typedef unsigned int uint;
typedef unsigned char uchar;
typedef _Float16 half2v __attribute__((ext_vector_type(2)));

__device__ __forceinline__ int dot4(uint a, uint b, int c) {
  return __builtin_amdgcn_sdot4((int)a, (int)b, c, false);
}
__device__ __forceinline__ uint pkh(float a, float b) {
  return __builtin_bit_cast(uint, __builtin_amdgcn_cvt_pkrtz(a, b));
}
__device__ __forceinline__ half2v uph(uint u) { return __builtin_bit_cast(half2v, u); }
__device__ __forceinline__ float fdot2u(uint a, uint b, float c) {
  return __builtin_amdgcn_fdot2(uph(a), uph(b), c, false);
}
#define IDPP(v, c) __builtin_amdgcn_mov_dpp((v), (c), 0xF, 0xF, true)
__device__ __forceinline__ int qsum(int v) {  // quad butterfly sum (VALU only)
  v += IDPP(v, 0xB1);  // xor 1
  v += IDPP(v, 0x4E);  // xor 2
  return v;
}
__device__ __forceinline__ float rcp_f(float x) { return __builtin_amdgcn_rcpf(x); }
__device__ __forceinline__ float sigm(float x) { return rcp_f(1.0f + __expf(-x)); }
__device__ __forceinline__ float tanh_f(float x) {
  return 1.0f - 2.0f * rcp_f(__expf(2.0f * x) + 1.0f);
}

// ---------- Wfold = W_proj @ W_ih (fp32) ----------
__global__ void fold_f32(const float* __restrict__ Wproj, const float* __restrict__ Wih,
                         float* __restrict__ Wfold) {
  int idx = blockIdx.x * blockDim.x + threadIdx.x;
  if (idx >= 64 * 1024) return;
  int d = idx >> 10, n = idx & 1023;
  float a = 0.f;
  for (int k = 0; k < 256; ++k) a += Wproj[d * 256 + k] * Wih[k * 1024 + n];
  Wfold[d * 1024 + n] = a;
}

// bfold[n] = b_proj @ W_ih + b_lstm
__global__ void bfold_kernel(const float* __restrict__ bproj, const float* __restrict__ Wih,
                             const float* __restrict__ blstm, float* __restrict__ bfold) {
  int n = blockIdx.x * blockDim.x + threadIdx.x;
  if (n >= 1024) return;
  float a = blstm[n];
  for (int k = 0; k < 256; ++k) a += bproj[k] * Wih[k * 1024 + n];
  bfold[n] = a;
}

// ---------- quantize weights, per-matrix scales ----------
// WhQ (scan, reg-resident): col-major-K: WhQ[c*64 + k4], c<1024 = Whh col (ifgo),
//   c in [1024,1280) = Whg col; k = 4*k4 + bb.
// XQ (pre): uint idx c*16 + k4; c<1024 Wfold col, else Wmk col (K=64).
// EQ (pre): uint idx c*8 + k4 (K=32).
__global__ __launch_bounds__(1024) void quant_all(
    const float* __restrict__ Whh, const float* __restrict__ Whg,
    const float* __restrict__ Wfold, const float* __restrict__ Wmk,
    const float* __restrict__ We,
    uint* __restrict__ WhQ, uint* __restrict__ XQ, uint* __restrict__ EQ,
    float* __restrict__ scales) {
  const int bid = blockIdx.x, tid = threadIdx.x;
  const float* src;
  int nelem;
  switch (bid) {
    case 0: src = Whh;   nelem = 262144; break;
    case 1: src = Whg;   nelem = 65536;  break;
    case 2: src = Wfold; nelem = 65536;  break;
    case 3: src = Wmk;   nelem = 16384;  break;
    default: src = We;   nelem = 8192;   break;
  }
  float m = 0.f;
  for (int i = tid; i < nelem; i += 1024) m = fmaxf(m, fabsf(src[i]));
#pragma unroll
  for (int d = 1; d < 64; d <<= 1) m = fmaxf(m, __shfl_xor(m, d));
  __shared__ float wm[16];
  if ((tid & 63) == 0) wm[tid >> 6] = m;
  __syncthreads();
  float mg = wm[0];
#pragma unroll
  for (int i = 1; i < 16; ++i) mg = fmaxf(mg, wm[i]);
  mg = fmaxf(mg, 1e-8f);
  if (tid == 0) scales[bid] = mg * (1.0f / 127.0f);
  const float inv = 127.0f / mg;

  if (bid == 0) {  // Whh -> WhQ[0..65536): c = i>>6, k4 = i&63
    for (int i = tid; i < 65536; i += 1024) {
      int c = i >> 6, k4 = i & 63;
      uint d = 0;
#pragma unroll
      for (int bb = 0; bb < 4; ++bb) {
        int qv = __float2int_rn(Whh[(4 * k4 + bb) * 1024 + c] * inv);
        qv = max(-127, min(127, qv));
        d |= ((uint)(qv & 0xff)) << (8 * bb);
      }
      WhQ[i] = d;
    }
  } else if (bid == 1) {  // Whg -> WhQ[65536..81920): j = i>>6, k4 = i&63
    for (int i = tid; i < 16384; i += 1024) {
      int j = i >> 6, k4 = i & 63;
      uint d = 0;
#pragma unroll
      for (int bb = 0; bb < 4; ++bb) {
        int qv = __float2int_rn(Whg[(4 * k4 + bb) * 256 + j] * inv);
        qv = max(-127, min(127, qv));
        d |= ((uint)(qv & 0xff)) << (8 * bb);
      }
      WhQ[65536 + i] = d;
    }
  } else if (bid == 2) {  // Wfold -> XQ[0..16384)
    for (int i = tid; i < 16384; i += 1024) {
      int c = i >> 4, k4 = i & 15;
      uint d = 0;
#pragma unroll
      for (int bb = 0; bb < 4; ++bb) {
        int qv = __float2int_rn(Wfold[(4 * k4 + bb) * 1024 + c] * inv);
        qv = max(-127, min(127, qv));
        d |= ((uint)(qv & 0xff)) << (8 * bb);
      }
      XQ[i] = d;
    }
  } else if (bid == 3) {  // Wmk -> XQ[16384..20480)
    for (int i = tid; i < 4096; i += 1024) {
      int j = i >> 4, k4 = i & 15;
      uint d = 0;
#pragma unroll
      for (int bb = 0; bb < 4; ++bb) {
        int qv = __float2int_rn(Wmk[(4 * k4 + bb) * 256 + j] * inv);
        qv = max(-127, min(127, qv));
        d |= ((uint)(qv & 0xff)) << (8 * bb);
      }
      XQ[16384 + i] = d;
    }
  } else {  // We -> EQ[0..2048)
    for (int i = tid; i < 2048; i += 1024) {
      int c = i >> 3, k4 = i & 7;
      uint d = 0;
#pragma unroll
      for (int bb = 0; bb < 4; ++bb) {
        int qv = __float2int_rn(We[(4 * k4 + bb) * 256 + c] * inv);
        qv = max(-127, min(127, qv));
        d |= ((uint)(qv & 0xff)) << (8 * bb);
      }
      EQ[i] = d;
    }
  }
}

// ---------- pack Wp1 [256][128] -> f16 k-pairs: WQ[j*128 + kp] ----------
__global__ void pack_wp1h(const float* __restrict__ Wp1, uint* __restrict__ WQ) {
  int idx = blockIdx.x * blockDim.x + threadIdx.x;
  if (idx >= 16384) return;
  int j = idx >> 7, kp = idx & 127;
  WQ[idx] = pkh(Wp1[(2 * kp) * 128 + j], Wp1[(2 * kp + 1) * 128 + j]);
}

// ---------- per-(b,t) input quantization + scl={xsc,esc,fac,0} ----------
__global__ __launch_bounds__(256) void prep_inputs(
    const float* __restrict__ x, const float* __restrict__ ev, const float* __restrict__ td,
    const float* __restrict__ decay, uint* __restrict__ xq, uint* __restrict__ eq,
    float4* __restrict__ scl) {
  int wid = threadIdx.x >> 6, lane = threadIdx.x & 63;
  int bt = blockIdx.x * 4 + wid;
  if (bt >= BT) return;
  float xv = x[(size_t)bt * DIN + lane];
  float evv = (lane < EE) ? ev[(size_t)bt * EE + lane] : 0.0f;
  float ax = fabsf(xv), ae = fabsf(evv);
#pragma unroll
  for (int m = 1; m < 64; m <<= 1) {
    ax = fmaxf(ax, __shfl_xor(ax, m));
    ae = fmaxf(ae, __shfl_xor(ae, m));
  }
  float mgx = fmaxf(ax, 1e-8f), mge = fmaxf(ae, 1e-8f);
  int qx = __float2int_rn(xv * (127.0f / mgx));
  qx = max(-127, min(127, qx));
  int qe = __float2int_rn(evv * (127.0f / mge));
  qe = max(-127, min(127, qe));
  uint dx = 0, de = 0;
#pragma unroll
  for (int b = 0; b < 4; ++b) dx |= ((uint)(__shfl(qx, lane * 4 + b) & 0xff)) << (8 * b);
#pragma unroll
  for (int b = 0; b < 4; ++b) de |= ((uint)(__shfl(qe, lane * 4 + b) & 0xff)) << (8 * b);
  if (lane < 16) xq[(size_t)bt * 16 + lane] = dx;
  if (lane < 8) eq[(size_t)bt * 8 + lane] = de;
  if (lane == 0) {
    float sp = log1pf(__expf(decay[0]));
    scl[bt] = make_float4(mgx * (1.0f / 127.0f), mge * (1.0f / 127.0f),
                          __expf(-sp * td[bt]), 0.0f);
  }
}

// ---------- output 2: first temporal difference ----------
__global__ void d1_kernel(const float* __restrict__ x, float* __restrict__ out2) {
  int idx = blockIdx.x * blockDim.x + threadIdx.x;
  const int per_t = DIN / 4;
  if (idx >= BB * TT * per_t) return;
  int t = (idx / per_t) % TT;
  float4 cur = reinterpret_cast<const float4*>(x)[idx];
  float4 res;
  if (t == 0) {
    res = make_float4(0.f, 0.f, 0.f, 0.f);
  } else {
    float4 prv = reinterpret_cast<const float4*>(x)[idx - per_t];
    res = make_float4(cur.x - prv.x, cur.y - prv.y, cur.z - prv.z, cur.w - prv.w);
  }
  reinterpret_cast<float4*>(out2)[idx] = res;
}

// ---------- precompute x/e-side per (bt, j): preA={f16 ifgo+bias}, preB={mkS,EF} f16 ----------
// 1024 thr = 256 j x 4 K-quarters q; DPP quad-reduce; lane q=0 stores.
__global__ __launch_bounds__(1024) void pre2(
    int t0, int lsteps,
    const uint* __restrict__ XQ, const uint* __restrict__ EQ,
    const float* __restrict__ scales, const float* __restrict__ bfold,
    const float* __restrict__ bmk, const float* __restrict__ be,
    const uint* __restrict__ xq, const uint* __restrict__ eqp,
    const float4* __restrict__ scl,
    uint2* __restrict__ preA, uint* __restrict__ preB) {
  const int tid = threadIdx.x;
  const int j = tid >> 2, q = tid & 3;

  uint4 wx[4];
#pragma unroll
  for (int g = 0; g < 4; ++g)
    wx[g] = *(const uint4*)(XQ + (g * 256 + j) * 16 + q * 4);
  const uint4 wmv = *(const uint4*)(XQ + 16384 + j * 16 + q * 4);
  const uint2 wev = *(const uint2*)(EQ + j * 8 + q * 2);
  float bf[4];
#pragma unroll
  for (int g = 0; g < 4; ++g) bf[g] = bfold[g * 256 + j];
  const float bmkv = bmk[j], bev = be[j];
  const float sXF = scales[2], sMK = scales[3], sE = scales[4];
  const int steps = 1 << lsteps;

  for (int it = 0; it < 64; ++it) {
    const int idx = blockIdx.x * 64 + it;
    const int b = idx >> lsteps, tl = idx & (steps - 1);
    const int bt = b * TT + t0 + tl;
    const uint4 X = *(const uint4*)(xq + (size_t)bt * 16 + q * 4);
    const uint2 E = *(const uint2*)(eqp + (size_t)bt * 8 + q * 2);
    const float4 sv = scl[bt];

    int a0 = 0, a1 = 0, a2 = 0, a3 = 0, am = 0, ae = 0;
    a0 = dot4(wx[0].x, X.x, a0); a0 = dot4(wx[0].y, X.y, a0);
    a0 = dot4(wx[0].z, X.z, a0); a0 = dot4(wx[0].w, X.w, a0);
    a1 = dot4(wx[1].x, X.x, a1); a1 = dot4(wx[1].y, X.y, a1);
    a1 = dot4(wx[1].z, X.z, a1); a1 = dot4(wx[1].w, X.w, a1);
    a2 = dot4(wx[2].x, X.x, a2); a2 = dot4(wx[2].y, X.y, a2);
    a2 = dot4(wx[2].z, X.z, a2); a2 = dot4(wx[2].w, X.w, a2);
    a3 = dot4(wx[3].x, X.x, a3); a3 = dot4(wx[3].y, X.y, a3);
    a3 = dot4(wx[3].z, X.z, a3); a3 = dot4(wx[3].w, X.w, a3);
    am = dot4(wmv.x, X.x, am);   am = dot4(wmv.y, X.y, am);
    am = dot4(wmv.z, X.z, am);   am = dot4(wmv.w, X.w, am);
    ae = dot4(wev.x, E.x, ae);   ae = dot4(wev.y, E.y, ae);

    a0 = qsum(a0); a1 = qsum(a1); a2 = qsum(a2);
    a3 = qsum(a3); am = qsum(am); ae = qsum(ae);

    if (q == 0) {
      const float fx = sXF * sv.x;
      const float p0 = (float)a0 * fx + bf[0];
      const float p1 = (float)a1 * fx + bf[1];
      const float p2 = (float)a2 * fx + bf[2];
      const float p3 = (float)a3 * fx + bf[3];
      const float mkS = sigm((float)am * (sMK * sv.x) + bmkv);
      const float EF = tanh_f((float)ae * (sE * sv.y) + bev) * sv.z;
      preA[(size_t)idx * 256 + j] = make_uint2(pkh(p0, p1), pkh(p2, p3));
      preB[(size_t)idx * 256 + j] = pkh(mkS, EF);
    }
  }
}

// ---------- the scan: 512 thr = (j, K-half); weights 160 uints reg-resident ----------
// Launch bounds WITHOUT a min-waves constraint: 8 waves/block must co-reside anyway
// (2 waves/SIMD), giving the allocator up to ~1024 unified regs/wave — room to keep
// the 160 weight uints in arch VGPRs instead of AGPRs (kills per-dot4 copy traffic).
__global__ __launch_bounds__(512) void scan4(
    int t0, int steps, const uint* __restrict__ WhQ,
    const float* __restrict__ scales, const float* __restrict__ bhg,
    const uint2* __restrict__ preA, const uint* __restrict__ preB,
    uchar* __restrict__ hB, float* __restrict__ cB, float* __restrict__ feat) {
  __shared__ __align__(16) uint hqW[128];  // double-buffered int8 h (512 B)
  const int tid = threadIdx.x, b = blockIdx.x;
  const int j = tid >> 1, kh = tid & 1;

  // 5 gates x 8 uint4 (this thread's K-half) = 160 regs
  const uint4* wv = (const uint4*)WhQ;
  uint4 wh[4][8];
#pragma unroll
  for (int g = 0; g < 4; ++g)
#pragma unroll
    for (int m = 0; m < 8; ++m) wh[g][m] = wv[(g * 256 + j) * 16 + kh * 8 + m];
  uint4 wg[8];
#pragma unroll
  for (int m = 0; m < 8; ++m) wg[m] = wv[(1024 + j) * 16 + kh * 8 + m];

  float c;
  if (t0 == 0) {
    c = 0.0f;
    if (tid < 64) hqW[tid] = 0u;
  } else {
    c = cB[b * 256 + j];
    if (tid < 64) hqW[tid] = ((const uint*)hB)[b * 64 + tid];
  }
  const float kHH = scales[0] * (1.0f / 127.0f);
  const float kHG = scales[1] * (1.0f / 127.0f);
  const float bhgv = bhg[j];
  const uint2* pA = preA + (size_t)b * steps * 256;
  const uint* pB = preB + (size_t)b * steps * 256;
  float* fout = feat + ((size_t)b * TT + t0) * HH;
  int buf = 0;
  __syncthreads();

  uint2 PA = pA[j];
  uint PB = pB[j];
#pragma unroll 2
  for (int t = 0; t < steps; ++t) {
    // prefetch next step's records (safe over-read into following ws region)
    const uint2 PAn = pA[(size_t)(t + 1) * 256 + j];
    const uint PBn = pB[(size_t)(t + 1) * 256 + j];

    int a0 = 0, a1 = 0, a2 = 0, a3 = 0, a4 = 0;
    const uint4* hp = (const uint4*)((const uchar*)hqW + buf * 256 + kh * 128);
#pragma unroll
    for (int m = 0; m < 8; ++m) {
      const uint4 hv = hp[m];
      a0 = dot4(wh[0][m].x, hv.x, a0); a0 = dot4(wh[0][m].y, hv.y, a0);
      a0 = dot4(wh[0][m].z, hv.z, a0); a0 = dot4(wh[0][m].w, hv.w, a0);
      a1 = dot4(wh[1][m].x, hv.x, a1); a1 = dot4(wh[1][m].y, hv.y, a1);
      a1 = dot4(wh[1][m].z, hv.z, a1); a1 = dot4(wh[1][m].w, hv.w, a1);
      a2 = dot4(wh[2][m].x, hv.x, a2); a2 = dot4(wh[2][m].y, hv.y, a2);
      a2 = dot4(wh[2][m].z, hv.z, a2); a2 = dot4(wh[2][m].w, hv.w, a2);
      a3 = dot4(wh[3][m].x, hv.x, a3); a3 = dot4(wh[3][m].y, hv.y, a3);
      a3 = dot4(wh[3][m].z, hv.z, a3); a3 = dot4(wh[3][m].w, hv.w, a3);
      a4 = dot4(wg[m].x, hv.x, a4);    a4 = dot4(wg[m].y, hv.y, a4);
      a4 = dot4(wg[m].z, hv.z, a4);    a4 = dot4(wg[m].w, hv.w, a4);
    }
    // pair reduce (lane 2j <-> 2j+1)
    a0 += __shfl_xor(a0, 1);
    a1 += __shfl_xor(a1, 1);
    a2 += __shfl_xor(a2, 1);
    a3 += __shfl_xor(a3, 1);
    a4 += __shfl_xor(a4, 1);

    const half2v pif = uph(PA.x), pgo = uph(PA.y), mkEF = uph(PB);
    const float p0 = (float)a0 * kHH + (float)pif.x;
    const float p1 = (float)a1 * kHH + (float)pif.y;
    const float p2 = (float)a2 * kHH + (float)pgo.x;
    const float p3 = (float)a3 * kHH + (float)pgo.y;
    const float p4 = (float)a4 * kHG + bhgv;
    const float mkS = (float)mkEF.x;
    const float EF = (float)mkEF.y;

    // Branchless kh-split elementwise: each lane of the pair computes one half,
    // exchanged via shfl_xor(.,1). Trans instr per wave-step: 14 -> 8.
    const bool hi = (kh != 0);
    const float t1 = sigm(hi ? p4 : p0);             // kh1: sigm(hg) | kh0: sigm(i)
    const float t2 = tanh_f(hi ? (EF * t1) : p2);    // kh1: tanh(impact) | kh0: tanh(g)
    const float u = (hi ? mkS : t1) * t2;            // kh1: mk*tanh(imp) | kh0: i*g
    const float t3 = sigm(hi ? p3 : p1);             // kh1: sigm(o) | kh0: sigm(f)
    const float ux = __shfl_xor(u, 1);               // kh0 receives kh1's term
    c = t3 * c + u + ux;                             // valid on kh0 only
    const float s3 = __shfl_xor(t3, 1);              // kh0 receives sigm(o)
    const float hn = s3 * tanh_f(c);                 // valid on kh0 only

    if (kh == 0) {
      fout[(size_t)t * HH + j] = hn;
      int qi = __float2int_rn(hn * 127.0f);
      ((uchar*)hqW)[(buf ^ 1) * 256 + j] = (uchar)(qi & 0xff);
    }
    __syncthreads();
    buf ^= 1;
    PA = PAn;
    PB = PBn;
  }
  if (kh == 0) cB[b * 256 + j] = c;
  if (tid < 64) ((uint*)hB)[b * 64 + tid] = hqW[buf * 64 + tid];
}

// ---------- predictor: f16 pairs + v_dot2; 128 rows/block; thread=(j, K-half) ----------
__global__ __launch_bounds__(256) void pred3(
    const float* __restrict__ feat, const uint* __restrict__ WQh,
    const float* __restrict__ bp1, const float* __restrict__ Wp2,
    const float* __restrict__ bp2, float* __restrict__ out0) {
  __shared__ uint WL[16384];       // W1 f16-pairs [j][kp] (64 KB)
  __shared__ uint hT[128 * 132];   // h f16-pairs [row][kp], padded stride (67.6 KB)
  __shared__ float psum[4][128];

  const int tid = threadIdx.x, w = tid >> 6, l = tid & 63;
  const int rbase = blockIdx.x * 128;

  for (int i = tid; i < 16384; i += 256) WL[i] = WQh[i];
  for (int i = tid; i < 16384; i += 256) {
    int row = i >> 7, kp = i & 127;
    const float2 hv = ((const float2*)feat)[(size_t)(rbase + row) * 128 + kp];
    hT[row * 132 + kp] = pkh(hv.x, hv.y);
  }
  __syncthreads();

  float ma[32], mb[32];
#pragma unroll
  for (int jj = 0; jj < 32; ++jj) {
    const float bv = bp1[w * 32 + jj];
    ma[jj] = bv;
    mb[jj] = bv;
  }
  const uint* ha = &hT[l * 132];
  const uint* hb = &hT[(l + 64) * 132];
  const uint* wbase = &WL[(w * 32) * 128];
  for (int kp4 = 0; kp4 < 32; ++kp4) {
    const uint4 a4 = *(const uint4*)&ha[kp4 * 4];
    const uint4 b4 = *(const uint4*)&hb[kp4 * 4];
#pragma unroll
    for (int jj = 0; jj < 32; ++jj) {
      const uint4 w4 = *(const uint4*)&wbase[jj * 128 + kp4 * 4];
      ma[jj] = fdot2u(w4.x, a4.x, ma[jj]);
      ma[jj] = fdot2u(w4.y, a4.y, ma[jj]);
      ma[jj] = fdot2u(w4.z, a4.z, ma[jj]);
      ma[jj] = fdot2u(w4.w, a4.w, ma[jj]);
      mb[jj] = fdot2u(w4.x, b4.x, mb[jj]);
      mb[jj] = fdot2u(w4.y, b4.y, mb[jj]);
      mb[jj] = fdot2u(w4.z, b4.z, mb[jj]);
      mb[jj] = fdot2u(w4.w, b4.w, mb[jj]);
    }
  }
  float accA = 0.f, accB = 0.f;
#pragma unroll
  for (int jj = 0; jj < 32; ++jj) {
    const float w2v = Wp2[w * 32 + jj];
    accA += 0.5f * ma[jj] * (1.0f + erff(ma[jj] * 0.70710678118f)) * w2v;
    accB += 0.5f * mb[jj] * (1.0f + erff(mb[jj] * 0.70710678118f)) * w2v;
  }
  psum[w][l] = accA;
  psum[w][64 + l] = accB;
  __syncthreads();
  if (tid < 128)
    out0[rbase + tid] =
        psum[0][tid] + psum[1][tid] + psum[2][tid] + psum[3][tid] + bp2[0];
}

extern "C" void kernel_launch(void* const* d_in, const int* in_sizes, int n_in,
                              void* d_out, int out_size, void* d_ws, size_t ws_size,
                              hipStream_t stream) {
  const float* x = (const float*)d_in[0];
  const float* ev = (const float*)d_in[1];
  const float* td = (const float*)d_in[2];
  const float* Wproj = (const float*)d_in[3];
  const float* bproj = (const float*)d_in[4];
  const float* Wih = (const float*)d_in[5];
  const float* Whh = (const float*)d_in[6];
  const float* blstm = (const float*)d_in[7];
  const float* Wmk = (const float*)d_in[8];
  const float* bmk = (const float*)d_in[9];
  const float* We = (const float*)d_in[10];
  const float* be = (const float*)d_in[11];
  const float* Whg = (const float*)d_in[12];
  const float* bhg = (const float*)d_in[13];
  const float* decay = (const float*)d_in[14];
  const float* Wp1 = (const float*)d_in[15];
  const float* bp1 = (const float*)d_in[16];
  const float* Wp2 = (const float*)d_in[17];
  const float* bp2 = (const float*)d_in[18];

  float* out0 = (float*)d_out;                // predictions [B,T,1]
  float* out1 = out0 + (size_t)BT;            // features    [B,T,H]
  float* out2 = out1 + (size_t)BT * HH;       // tmdo d1     [B,T,64]

  char* w = (char*)d_ws;
  float* Wfold_f = (float*)w; w += (size_t)65536 * 4;   // 256 KB
  uint* WhQ = (uint*)w; w += (size_t)81920 * 4;         // 320 KB (Whh ifgo + Whg)
  uint* XQ = (uint*)w; w += (size_t)20480 * 4;          // 80 KB
  uint* EQ = (uint*)w; w += (size_t)2048 * 4;           // 8 KB
  uint* WQh = (uint*)w; w += (size_t)16384 * 4;         // 64 KB
  float* scales = (float*)w; w += 16 * 4;
  float* bfold = (float*)w; w += 1024 * 4;
  uchar* hB = (uchar*)w; w += (size_t)BB * 256;         // 32 KB int8 h state
  float* cB = (float*)w; w += (size_t)BB * 256 * 4;     // 128 KB c state
  uint* xq = (uint*)w; w += (size_t)BT * 16 * 4;        // 8 MB
  uint* eq = (uint*)w; w += (size_t)BT * 8 * 4;         // 4 MB
  float4* scl = (float4*)w; w += (size_t)BT * 16;       // 2 MB

  // size the T-chunk from remaining workspace (preA+preB = 12 B/record)
  size_t used = (size_t)(w - (char*)d_ws);
  size_t avail = (ws_size > used + 8192) ? (ws_size - used - 8192) : 0;
  int steps = TT, lsteps = 10;
  while (steps > 4 && (size_t)BB * (size_t)steps * 256 * 12 > avail) {
    steps >>= 1;
    lsteps--;
  }
  uint2* preA = (uint2*)w; w += (size_t)BB * steps * 256 * 8;
  uint* preB = (uint*)w;

  hipLaunchKernelGGL(fold_f32, dim3(256), dim3(256), 0, stream, Wproj, Wih, Wfold_f);
  hipLaunchKernelGGL(bfold_kernel, dim3(4), dim3(256), 0, stream, bproj, Wih, blstm, bfold);
  hipLaunchKernelGGL(quant_all, dim3(5), dim3(1024), 0, stream,
                     Whh, Whg, Wfold_f, Wmk, We, WhQ, XQ, EQ, scales);
  hipLaunchKernelGGL(pack_wp1h, dim3(64), dim3(256), 0, stream, Wp1, WQh);
  hipLaunchKernelGGL(prep_inputs, dim3(BT / 4), dim3(256), 0, stream,
                     x, ev, td, decay, xq, eq, scl);
  hipLaunchKernelGGL(d1_kernel, dim3(8192), dim3(256), 0, stream, x, out2);

  for (int t0 = 0; t0 < TT; t0 += steps) {
    hipLaunchKernelGGL(pre2, dim3(BB * steps / 64), dim3(1024), 0, stream,
                       t0, lsteps, XQ, EQ, scales, bfold, bmk, be, xq, eq, scl,
                       preA, preB);
    hipLaunchKernelGGL(scan4, dim3(BB), dim3(512), 0, stream,
                       t0, steps, WhQ, scales, bhg, preA, preB, hB, cB, out1);
  }

  hipLaunchKernelGGL(pred3, dim3(BT / 128), dim3(256), 0, stream,
                     out1, WQh, bp1, Wp2, bp2, out0);
}